// Round 6
// baseline (242.841 us; speedup 1.0000x reference)
//
#include <hip/hip_runtime.h>

typedef __attribute__((ext_vector_type(8))) short bf16x8;
typedef __attribute__((ext_vector_type(4))) float f32x4;

__device__ __forceinline__ float bf2f(unsigned short u) {
    unsigned int x = ((unsigned int)u) << 16;
    float f;
    __builtin_memcpy(&f, &x, 4);
    return f;
}
__device__ __forceinline__ unsigned short f2bf(float f) {
    unsigned int x;
    __builtin_memcpy(&x, &f, 4);
    x += 0x7FFFu + ((x >> 16) & 1u);
    return (unsigned short)(x >> 16);
}

// Async global->LDS: HW writes lds[base + lane*16]; gptr is per-lane.
#define GLOAD_LDS16(gp, lp)                                      \
    __builtin_amdgcn_global_load_lds(                            \
        (const __attribute__((address_space(1))) void*)(gp),     \
        (__attribute__((address_space(3))) void*)(lp), 16, 0, 0)

// -------------------------------------------------------------------------
// Fused preprocessing: one launch instead of three.
// blocks [0,4096):        cast x f32 -> bf16 (4 elems/thread)
// blocks [4096,16384):    fold_lora attn  (3072x1024)
// blocks [16384,20480):   fold_lora proj  (1024x1024)
__global__ __launch_bounds__(256) void prep(
    const float* __restrict__ x, unsigned short* __restrict__ xb,
    const float* __restrict__ w_attn, const float* __restrict__ la_attn,
    const float* __restrict__ lb_attn, unsigned short* __restrict__ Weff_attn,
    const float* __restrict__ w_proj, const float* __restrict__ la_proj,
    const float* __restrict__ lb_proj, unsigned short* __restrict__ Weff_proj) {
    const int bid = blockIdx.x;
    if (bid < 4096) {
        int i = (bid * 256 + threadIdx.x) * 4;
        float4 v = *(const float4*)(x + i);
        xb[i + 0] = f2bf(v.x);
        xb[i + 1] = f2bf(v.y);
        xb[i + 2] = f2bf(v.z);
        xb[i + 3] = f2bf(v.w);
        return;
    }
    const float* W;
    const float* Ain;
    const float* Bin;
    unsigned short* Weff;
    int idx;
    if (bid < 16384) {
        idx = (bid - 4096) * 256 + threadIdx.x;
        W = w_attn; Ain = la_attn; Bin = lb_attn; Weff = Weff_attn;
    } else {
        idx = (bid - 16384) * 256 + threadIdx.x;
        W = w_proj; Ain = la_proj; Bin = lb_proj; Weff = Weff_proj;
    }
    int n = idx >> 10;
    int k = idx & 1023;
    float s = 0.f;
#pragma unroll
    for (int r = 0; r < 16; ++r)
        s += Bin[n * 16 + r] * Ain[r * 1024 + k];
    Weff[idx] = f2bf(W[idx] + 0.0625f * s);
}

// -------------------------------------------------------------------------
// C[M][N] = A[M][K] @ B[N][K]^T + bias[N].  A,B bf16; bias float; fp32 acc.
// m97 structure: global_load_lds width=16 staging, 2 barriers per K-step.
template <bool F32OUT>
__global__ __launch_bounds__(256) void gemm_bt_bias(
    const unsigned short* __restrict__ A, const unsigned short* __restrict__ B,
    const float* __restrict__ bias, unsigned short* __restrict__ Cb,
    float* __restrict__ Cf, int M, int N, int K) {
    __shared__ unsigned short sA[128 * 32];
    __shared__ unsigned short sB[128 * 32];
    const int tid = threadIdx.x;
    const int wave = tid >> 6, lane = tid & 63;
    const int quad = lane >> 4, l16 = lane & 15;
    const int m0 = blockIdx.y * 128, n0 = blockIdx.x * 128;
    const int wm = (wave & 1) * 64, wn = (wave >> 1) * 64;

    const int srow = wave * 32 + (lane >> 2);
    const int scol = (lane & 3) * 8;
    const unsigned short* Ag = A + (size_t)(m0 + srow) * K + scol;
    const unsigned short* Bg = B + (size_t)(n0 + srow) * K + scol;
    unsigned short* sAw = sA + wave * 1024;
    unsigned short* sBw = sB + wave * 1024;
    const size_t kjump = (size_t)16 * K;

    f32x4 acc[4][4];
#pragma unroll
    for (int i = 0; i < 4; ++i)
#pragma unroll
        for (int j = 0; j < 4; ++j) acc[i][j] = (f32x4){0.f, 0.f, 0.f, 0.f};

    for (int k0 = 0; k0 < K; k0 += 32) {
        __syncthreads();  // previous tile's LDS reads done
        GLOAD_LDS16(Ag + k0, sAw);
        GLOAD_LDS16(Ag + k0 + kjump, sAw + 512);
        GLOAD_LDS16(Bg + k0, sBw);
        GLOAD_LDS16(Bg + k0 + kjump, sBw + 512);
        __syncthreads();  // drains vmcnt(0): tile resident
        bf16x8 af[4], bfr[4];
#pragma unroll
        for (int mi = 0; mi < 4; ++mi)
            af[mi] = *(const bf16x8*)&sA[(wm + mi * 16 + l16) * 32 + quad * 8];
#pragma unroll
        for (int ni = 0; ni < 4; ++ni)
            bfr[ni] = *(const bf16x8*)&sB[(wn + ni * 16 + l16) * 32 + quad * 8];
#pragma unroll
        for (int mi = 0; mi < 4; ++mi)
#pragma unroll
            for (int ni = 0; ni < 4; ++ni)
                acc[mi][ni] = __builtin_amdgcn_mfma_f32_16x16x32_bf16(
                    af[mi], bfr[ni], acc[mi][ni], 0, 0, 0);
    }
    float bv[4];
#pragma unroll
    for (int ni = 0; ni < 4; ++ni) bv[ni] = bias[n0 + wn + ni * 16 + l16];
#pragma unroll
    for (int mi = 0; mi < 4; ++mi)
#pragma unroll
        for (int ni = 0; ni < 4; ++ni)
#pragma unroll
            for (int r = 0; r < 4; ++r) {
                int row = m0 + wm + mi * 16 + quad * 4 + r;
                int col = n0 + wn + ni * 16 + l16;
                float val = acc[mi][ni][r] + bv[ni];
                if (F32OUT)
                    Cf[(size_t)row * N + col] = val;
                else
                    Cb[(size_t)row * N + col] = f2bf(val);
            }
}

// -------------------------------------------------------------------------
// Vt[(b*16+h)][d][t] = qkv[b*2048+t][2048 + h*64 + d]   (bf16, verified r3)
__global__ __launch_bounds__(256) void transpose_v(
    const unsigned short* __restrict__ qkv, unsigned short* __restrict__ Vt) {
    const int b = blockIdx.z, h = blockIdx.y, t0 = blockIdx.x * 64;
    __shared__ unsigned short tile[64][68];
    const int tid = threadIdx.x;
    const int r = tid >> 3, c8 = (tid & 7) * 8;
    const unsigned short* src = qkv + (size_t)(b * 2048) * 3072 + 2048 + h * 64;
#pragma unroll
    for (int p = 0; p < 2; ++p) {
        int t = p * 32 + r;
        const unsigned short* s = src + (size_t)(t0 + t) * 3072 + c8;
#pragma unroll
        for (int j = 0; j < 8; ++j) tile[t][c8 + j] = s[j];
    }
    __syncthreads();
    unsigned short* dst = Vt + (size_t)((b * 16 + h) * 64) * 2048;
#pragma unroll
    for (int p = 0; p < 2; ++p) {
        int d = p * 32 + r;
        unsigned short* o = dst + (size_t)d * 2048 + t0 + c8;
#pragma unroll
        for (int j = 0; j < 8; ++j) o[j] = tile[c8 + j][d];
    }
}

// -------------------------------------------------------------------------
// Flash attention v8: v7 + NO LDS V-staging.
// v7's counters showed the LDS pipe ~67% busy + 23% conflict cycles: 26 DS
// ops/tile/wave dominated. V is L2/L3-resident (8 MB total, 256 KB per bh),
// so each wave now reads its PV B-fragments DIRECTLY from global Vt with the
// same per-lane bf16x8 pattern (issued before the barrier -> L2 latency
// hides under K-staging + QK^T). Removes sV writes + 8 sV reads per tile
// (26 -> 16 DS ops), the vr prefetch registers, and 9 KB LDS.
// K stays in LDS (4-wave reuse). Softmax: swapped-QK^T in-register (v7).
__global__ __launch_bounds__(256, 4) void attn_kernel(
    const unsigned short* __restrict__ qkv,  // [4096][3072] bf16
    const unsigned short* __restrict__ Vt,   // [32][64][2048] bf16
    unsigned short* __restrict__ y) {        // [4096][1024] bf16
    const int b = blockIdx.z, h = blockIdx.y;
    const int bh = b * 16 + h;
    const int qblk = (int)blockIdx.x ^ (((bh >> 3) & 1) ? 31 : 0);
    const int w = threadIdx.x >> 6, lane = threadIdx.x & 63;
    const int quad = lane >> 4, l16 = lane & 15;
    const int q0 = qblk * 64 + w * 16;
    const int ntiles = qblk + 1;

    __shared__ unsigned short sK[64 * 72];     // [kv][d]
    __shared__ unsigned short sP[4][16 * 72];  // per-wave P [q][kv]

    const unsigned short* Qb = qkv + (size_t)(b * 2048) * 3072 + h * 64;
    const unsigned short* Kg = Qb + 1024;
    const unsigned short* Vg = Vt + (size_t)(bh * 64) * 2048;

    const int rlo = threadIdx.x >> 3;       // 0..31
    const int c8 = (threadIdx.x & 7) * 8;   // 0..56

    bf16x8 qf0 = *(const bf16x8*)(Qb + (size_t)(q0 + l16) * 3072 + quad * 8);
    bf16x8 qf1 = *(const bf16x8*)(Qb + (size_t)(q0 + l16) * 3072 + 32 + quad * 8);

    // Per-thread V row bases: B-frag v0 = Vt[d = nt*16+l16][kv0 + quad*8 + j]
    const unsigned short* Vr0 = Vg + (size_t)(0 * 16 + l16) * 2048 + quad * 8;
    const unsigned short* Vr1 = Vg + (size_t)(1 * 16 + l16) * 2048 + quad * 8;
    const unsigned short* Vr2 = Vg + (size_t)(2 * 16 + l16) * 2048 + quad * 8;
    const unsigned short* Vr3 = Vg + (size_t)(3 * 16 + l16) * 2048 + quad * 8;

    f32x4 o[4];
    float lacc = 0.f;  // scalar: all this thread's P values belong to q=q0+l16
#pragma unroll
    for (int nt = 0; nt < 4; ++nt) o[nt] = (f32x4){0.f, 0.f, 0.f, 0.f};

    const float csc = 0.125f * 1.44269504088896340736f;  // (1/sqrt 64)*log2(e)

    bf16x8 kr0 = *(const bf16x8*)(Kg + (size_t)rlo * 3072 + c8);
    bf16x8 kr1 = *(const bf16x8*)(Kg + (size_t)(rlo + 32) * 3072 + c8);

    for (int it = 0; it < ntiles; ++it) {
        const int kv0 = it * 64;
        __syncthreads();  // sK buffer free
        *(bf16x8*)&sK[rlo * 72 + c8] = kr0;
        *(bf16x8*)&sK[(rlo + 32) * 72 + c8] = kr1;
        // V fragments for THIS tile, direct from global (L2/L3-resident).
        // Issued before the barrier: latency hides under staging + QK^T.
        bf16x8 vf0[4], vf1[4];
        vf0[0] = *(const bf16x8*)(Vr0 + kv0);
        vf1[0] = *(const bf16x8*)(Vr0 + kv0 + 32);
        vf0[1] = *(const bf16x8*)(Vr1 + kv0);
        vf1[1] = *(const bf16x8*)(Vr1 + kv0 + 32);
        vf0[2] = *(const bf16x8*)(Vr2 + kv0);
        vf1[2] = *(const bf16x8*)(Vr2 + kv0 + 32);
        vf0[3] = *(const bf16x8*)(Vr3 + kv0);
        vf1[3] = *(const bf16x8*)(Vr3 + kv0 + 32);
        if (it + 1 < ntiles) {  // prefetch next K tile; overlaps compute below
            const int nx = kv0 + 64;
            kr0 = *(const bf16x8*)(Kg + (size_t)(nx + rlo) * 3072 + c8);
            kr1 = *(const bf16x8*)(Kg + (size_t)(nx + rlo + 32) * 3072 + c8);
        }
        __syncthreads();  // sK ready

        // S^T[f][r]: q = q0+l16, kv = kv0 + f*16 + quad*4 + r
        f32x4 S[4];
#pragma unroll
        for (int f = 0; f < 4; ++f) {
            bf16x8 klo = *(const bf16x8*)&sK[(f * 16 + l16) * 72 + quad * 8];
            bf16x8 khi = *(const bf16x8*)&sK[(f * 16 + l16) * 72 + 32 + quad * 8];
            S[f] = (f32x4){0.f, 0.f, 0.f, 0.f};
            S[f] = __builtin_amdgcn_mfma_f32_16x16x32_bf16(klo, qf0, S[f], 0, 0, 0);
            S[f] = __builtin_amdgcn_mfma_f32_16x16x32_bf16(khi, qf1, S[f], 0, 0, 0);
        }
        const bool diag = (it == qblk);
        const int qr16 = w * 16 + l16;  // q position within the 64-row block
#pragma unroll
        for (int f = 0; f < 4; ++f) {
            float p0, p1, p2, p3;
            {
                float sv = S[f][0] * csc;
                asm("v_exp_f32 %0, %1" : "=v"(p0) : "v"(sv));
                sv = S[f][1] * csc;
                asm("v_exp_f32 %0, %1" : "=v"(p1) : "v"(sv));
                sv = S[f][2] * csc;
                asm("v_exp_f32 %0, %1" : "=v"(p2) : "v"(sv));
                sv = S[f][3] * csc;
                asm("v_exp_f32 %0, %1" : "=v"(p3) : "v"(sv));
            }
            if (diag) {  // mask: kv_local <= q_local
                int c = f * 16 + quad * 4;
                p0 = (c + 0 <= qr16) ? p0 : 0.f;
                p1 = (c + 1 <= qr16) ? p1 : 0.f;
                p2 = (c + 2 <= qr16) ? p2 : 0.f;
                p3 = (c + 3 <= qr16) ? p3 : 0.f;
            }
            lacc += (p0 + p1) + (p2 + p3);
            unsigned int d0, d1;
            asm("v_cvt_pk_bf16_f32 %0, %1, %2" : "=v"(d0) : "v"(p0), "v"(p1));
            asm("v_cvt_pk_bf16_f32 %0, %1, %2" : "=v"(d1) : "v"(p2), "v"(p3));
            *(uint2*)&sP[w][l16 * 72 + f * 16 + quad * 4] = (uint2){d0, d1};
        }
        asm volatile("" ::: "memory");  // order P stores before reload
        bf16x8 pf0 = *(const bf16x8*)&sP[w][l16 * 72 + quad * 8];
        bf16x8 pf1 = *(const bf16x8*)&sP[w][l16 * 72 + 32 + quad * 8];
#pragma unroll
        for (int nt = 0; nt < 4; ++nt) {
            o[nt] = __builtin_amdgcn_mfma_f32_16x16x32_bf16(pf0, vf0[nt], o[nt], 0, 0, 0);
            o[nt] = __builtin_amdgcn_mfma_f32_16x16x32_bf16(pf1, vf1[nt], o[nt], 0, 0, 0);
        }
    }

    // lacc holds a partial denom for q=q0+l16 (this thread's kv subset).
    // Full denom: sum over the 4 quads (lanes sharing l16).
    lacc += __shfl_xor(lacc, 16);
    lacc += __shfl_xor(lacc, 32);
    // Output rows of this thread are q0 + quad*4 + r; their denoms live in
    // lanes (quad*4+r) (which have l16 == quad*4+r).
    float lt[4];
#pragma unroll
    for (int r = 0; r < 4; ++r) lt[r] = __shfl(lacc, quad * 4 + r);

    unsigned short* yb = y + (size_t)(b * 2048) * 1024 + h * 64;
#pragma unroll
    for (int nt = 0; nt < 4; ++nt)
#pragma unroll
        for (int r = 0; r < 4; ++r)
            yb[(size_t)(q0 + quad * 4 + r) * 1024 + nt * 16 + l16] =
                f2bf(o[nt][r] / lt[r]);
}

// -------------------------------------------------------------------------
extern "C" void kernel_launch(void* const* d_in, const int* in_sizes, int n_in,
                              void* d_out, int out_size, void* d_ws, size_t ws_size,
                              hipStream_t stream) {
    const float* x       = (const float*)d_in[0];
    const float* w_attn  = (const float*)d_in[1];
    const float* b_attn  = (const float*)d_in[2];
    const float* la_attn = (const float*)d_in[3];
    const float* lb_attn = (const float*)d_in[4];
    const float* w_proj  = (const float*)d_in[5];
    const float* b_proj  = (const float*)d_in[6];
    const float* la_proj = (const float*)d_in[7];
    const float* lb_proj = (const float*)d_in[8];
    float* out = (float*)d_out;

    char* w = (char*)d_ws;
    unsigned short* xb        = (unsigned short*)w; w += (size_t)4096 * 1024 * 2;
    unsigned short* Weff_attn = (unsigned short*)w; w += (size_t)3072 * 1024 * 2;
    unsigned short* Weff_proj = (unsigned short*)w; w += (size_t)1024 * 1024 * 2;
    unsigned short* qkv       = (unsigned short*)w; w += (size_t)4096 * 3072 * 2;
    unsigned short* Vt        = (unsigned short*)w; w += (size_t)32 * 64 * 2048 * 2;
    unsigned short* y         = (unsigned short*)w; w += (size_t)4096 * 1024 * 2;

    prep<<<20480, 256, 0, stream>>>(x, xb, w_attn, la_attn, lb_attn, Weff_attn,
                                    w_proj, la_proj, lb_proj, Weff_proj);
    gemm_bt_bias<false><<<dim3(24, 32), 256, 0, stream>>>(
        xb, Weff_attn, b_attn, qkv, (float*)nullptr, 4096, 3072, 1024);
    transpose_v<<<dim3(32, 16, 2), 256, 0, stream>>>(qkv, Vt);
    attn_kernel<<<dim3(32, 16, 2), 256, 0, stream>>>(qkv, Vt, y);
    gemm_bt_bias<true><<<dim3(8, 32), 256, 0, stream>>>(
        y, Weff_proj, b_proj, (unsigned short*)nullptr, out, 4096, 1024, 1024);
}

// Round 7
// 206.906 us; speedup vs baseline: 1.1737x; 1.1737x over previous
//
#include <hip/hip_runtime.h>

typedef __attribute__((ext_vector_type(8))) short bf16x8;
typedef __attribute__((ext_vector_type(4))) short bf16x4;
typedef __attribute__((ext_vector_type(4))) float f32x4;

__device__ __forceinline__ float bf2f(unsigned short u) {
    unsigned int x = ((unsigned int)u) << 16;
    float f;
    __builtin_memcpy(&f, &x, 4);
    return f;
}
__device__ __forceinline__ unsigned short f2bf(float f) {
    unsigned int x;
    __builtin_memcpy(&x, &f, 4);
    x += 0x7FFFu + ((x >> 16) & 1u);
    return (unsigned short)(x >> 16);
}

// Async global->LDS: HW writes lds[base + lane*16]; gptr is per-lane.
#define GLOAD_LDS16(gp, lp)                                      \
    __builtin_amdgcn_global_load_lds(                            \
        (const __attribute__((address_space(1))) void*)(gp),     \
        (__attribute__((address_space(3))) void*)(lp), 16, 0, 0)

// -------------------------------------------------------------------------
// Fused preprocessing: one launch instead of three.
// blocks [0,4096):        cast x f32 -> bf16 (4 elems/thread)
// blocks [4096,16384):    fold_lora attn  (3072x1024)
// blocks [16384,20480):   fold_lora proj  (1024x1024)
__global__ __launch_bounds__(256) void prep(
    const float* __restrict__ x, unsigned short* __restrict__ xb,
    const float* __restrict__ w_attn, const float* __restrict__ la_attn,
    const float* __restrict__ lb_attn, unsigned short* __restrict__ Weff_attn,
    const float* __restrict__ w_proj, const float* __restrict__ la_proj,
    const float* __restrict__ lb_proj, unsigned short* __restrict__ Weff_proj) {
    const int bid = blockIdx.x;
    if (bid < 4096) {
        int i = (bid * 256 + threadIdx.x) * 4;
        float4 v = *(const float4*)(x + i);
        xb[i + 0] = f2bf(v.x);
        xb[i + 1] = f2bf(v.y);
        xb[i + 2] = f2bf(v.z);
        xb[i + 3] = f2bf(v.w);
        return;
    }
    const float* W;
    const float* Ain;
    const float* Bin;
    unsigned short* Weff;
    int idx;
    if (bid < 16384) {
        idx = (bid - 4096) * 256 + threadIdx.x;
        W = w_attn; Ain = la_attn; Bin = lb_attn; Weff = Weff_attn;
    } else {
        idx = (bid - 16384) * 256 + threadIdx.x;
        W = w_proj; Ain = la_proj; Bin = lb_proj; Weff = Weff_proj;
    }
    int n = idx >> 10;
    int k = idx & 1023;
    float s = 0.f;
#pragma unroll
    for (int r = 0; r < 16; ++r)
        s += Bin[n * 16 + r] * Ain[r * 1024 + k];
    Weff[idx] = f2bf(W[idx] + 0.0625f * s);
}

// -------------------------------------------------------------------------
// C[M][N] = A[M][K] @ B[N][K]^T + bias[N].  A,B bf16; bias float; fp32 acc.
// m97 structure: global_load_lds width=16 staging, 2 barriers per K-step.
// VSPLIT (qkv GEMM): tiles with n0 >= 2048 are the V third of qkv; their
// output is consumed ONLY as Vt[(b*16+h)*64+d][t], so write it transposed
// directly (4 consecutive t per thread -> one 8B store) and skip the dead
// qkv store. This eliminates the separate transpose_v kernel entirely.
template <bool F32OUT, bool VSPLIT>
__global__ __launch_bounds__(256) void gemm_bt_bias(
    const unsigned short* __restrict__ A, const unsigned short* __restrict__ B,
    const float* __restrict__ bias, unsigned short* __restrict__ Cb,
    float* __restrict__ Cf, unsigned short* __restrict__ Vtout,
    int M, int N, int K) {
    __shared__ unsigned short sA[128 * 32];
    __shared__ unsigned short sB[128 * 32];
    const int tid = threadIdx.x;
    const int wave = tid >> 6, lane = tid & 63;
    const int quad = lane >> 4, l16 = lane & 15;
    const int m0 = blockIdx.y * 128, n0 = blockIdx.x * 128;
    const int wm = (wave & 1) * 64, wn = (wave >> 1) * 64;

    const int srow = wave * 32 + (lane >> 2);
    const int scol = (lane & 3) * 8;
    const unsigned short* Ag = A + (size_t)(m0 + srow) * K + scol;
    const unsigned short* Bg = B + (size_t)(n0 + srow) * K + scol;
    unsigned short* sAw = sA + wave * 1024;
    unsigned short* sBw = sB + wave * 1024;
    const size_t kjump = (size_t)16 * K;

    f32x4 acc[4][4];
#pragma unroll
    for (int i = 0; i < 4; ++i)
#pragma unroll
        for (int j = 0; j < 4; ++j) acc[i][j] = (f32x4){0.f, 0.f, 0.f, 0.f};

    for (int k0 = 0; k0 < K; k0 += 32) {
        __syncthreads();  // previous tile's LDS reads done
        GLOAD_LDS16(Ag + k0, sAw);
        GLOAD_LDS16(Ag + k0 + kjump, sAw + 512);
        GLOAD_LDS16(Bg + k0, sBw);
        GLOAD_LDS16(Bg + k0 + kjump, sBw + 512);
        __syncthreads();  // drains vmcnt(0): tile resident
        bf16x8 af[4], bfr[4];
#pragma unroll
        for (int mi = 0; mi < 4; ++mi)
            af[mi] = *(const bf16x8*)&sA[(wm + mi * 16 + l16) * 32 + quad * 8];
#pragma unroll
        for (int ni = 0; ni < 4; ++ni)
            bfr[ni] = *(const bf16x8*)&sB[(wn + ni * 16 + l16) * 32 + quad * 8];
#pragma unroll
        for (int mi = 0; mi < 4; ++mi)
#pragma unroll
            for (int ni = 0; ni < 4; ++ni)
                acc[mi][ni] = __builtin_amdgcn_mfma_f32_16x16x32_bf16(
                    af[mi], bfr[ni], acc[mi][ni], 0, 0, 0);
    }
    float bv[4];
#pragma unroll
    for (int ni = 0; ni < 4; ++ni) bv[ni] = bias[n0 + wn + ni * 16 + l16];

    if (VSPLIT && n0 >= 2048) {
        // V tile: write transposed into Vt only.
        // col = n0+wn+ni*16+l16 -> hcol = col-2048; h = hcol>>6, d = hcol&63.
        // rows m0+wm+mi*16+quad*4+{0..3} are 4 consecutive t (8B store).
#pragma unroll
        for (int ni = 0; ni < 4; ++ni) {
            const int hcol = n0 + wn + ni * 16 + l16 - 2048;
#pragma unroll
            for (int mi = 0; mi < 4; ++mi) {
                const int rowtop = m0 + wm + mi * 16 + quad * 4;
                const int bb = rowtop >> 11;
                const int t = rowtop & 2047;
                bf16x4 pk;
#pragma unroll
                for (int r = 0; r < 4; ++r)
                    pk[r] = (short)f2bf(acc[mi][ni][r] + bv[ni]);
                *(bf16x4*)(Vtout +
                           ((size_t)((bb * 16 + (hcol >> 6)) * 64 + (hcol & 63))) *
                               2048 +
                           t) = pk;
            }
        }
        return;
    }

#pragma unroll
    for (int mi = 0; mi < 4; ++mi)
#pragma unroll
        for (int ni = 0; ni < 4; ++ni)
#pragma unroll
            for (int r = 0; r < 4; ++r) {
                int row = m0 + wm + mi * 16 + quad * 4 + r;
                int col = n0 + wn + ni * 16 + l16;
                float val = acc[mi][ni][r] + bv[ni];
                if (F32OUT)
                    Cf[(size_t)row * N + col] = val;
                else
                    Cb[(size_t)row * N + col] = f2bf(val);
            }
}

// -------------------------------------------------------------------------
// Flash attention v7 (reverted from v8): r3 scheduling + swapped-QK^T
// softmax. v8 (V direct from global) regressed: the __syncthreads barrier
// drain (s_waitcnt vmcnt(0)) exposed every V load's L2 latency on the
// critical path (VALUBusy 35->16%). LDS V staging restored.
__global__ __launch_bounds__(256) void attn_kernel(
    const unsigned short* __restrict__ qkv,  // [4096][3072] bf16
    const unsigned short* __restrict__ Vt,   // [32][64][2048] bf16
    unsigned short* __restrict__ y) {        // [4096][1024] bf16
    const int b = blockIdx.z, h = blockIdx.y;
    const int bh = b * 16 + h;
    const int qblk = (int)blockIdx.x ^ (((bh >> 3) & 1) ? 31 : 0);
    const int w = threadIdx.x >> 6, lane = threadIdx.x & 63;
    const int quad = lane >> 4, l16 = lane & 15;
    const int q0 = qblk * 64 + w * 16;
    const int ntiles = qblk + 1;

    __shared__ unsigned short sK[64 * 72];     // [kv][d]
    __shared__ unsigned short sV[64 * 72];     // [d][kv]
    __shared__ unsigned short sP[4][16 * 72];  // per-wave P [q][kv]

    const unsigned short* Qb = qkv + (size_t)(b * 2048) * 3072 + h * 64;
    const unsigned short* Kg = Qb + 1024;
    const unsigned short* Vg = Vt + (size_t)(bh * 64) * 2048;

    const int rlo = threadIdx.x >> 3;       // 0..31
    const int c8 = (threadIdx.x & 7) * 8;   // 0..56

    bf16x8 qf0 = *(const bf16x8*)(Qb + (size_t)(q0 + l16) * 3072 + quad * 8);
    bf16x8 qf1 = *(const bf16x8*)(Qb + (size_t)(q0 + l16) * 3072 + 32 + quad * 8);

    f32x4 o[4];
    float lacc = 0.f;  // scalar: all this thread's P values belong to q=q0+l16
#pragma unroll
    for (int nt = 0; nt < 4; ++nt) o[nt] = (f32x4){0.f, 0.f, 0.f, 0.f};

    const float csc = 0.125f * 1.44269504088896340736f;  // (1/sqrt 64)*log2(e)

    bf16x8 kr0 = *(const bf16x8*)(Kg + (size_t)rlo * 3072 + c8);
    bf16x8 kr1 = *(const bf16x8*)(Kg + (size_t)(rlo + 32) * 3072 + c8);
    bf16x8 vr0 = *(const bf16x8*)(Vg + (size_t)rlo * 2048 + c8);
    bf16x8 vr1 = *(const bf16x8*)(Vg + (size_t)(rlo + 32) * 2048 + c8);

    for (int it = 0; it < ntiles; ++it) {
        const int kv0 = it * 64;
        __syncthreads();  // buffer free
        *(bf16x8*)&sK[rlo * 72 + c8] = kr0;
        *(bf16x8*)&sK[(rlo + 32) * 72 + c8] = kr1;
        *(bf16x8*)&sV[rlo * 72 + c8] = vr0;
        *(bf16x8*)&sV[(rlo + 32) * 72 + c8] = vr1;
        if (it + 1 < ntiles) {  // prefetch next tile; overlaps compute below
            const int nx = kv0 + 64;
            kr0 = *(const bf16x8*)(Kg + (size_t)(nx + rlo) * 3072 + c8);
            kr1 = *(const bf16x8*)(Kg + (size_t)(nx + rlo + 32) * 3072 + c8);
            vr0 = *(const bf16x8*)(Vg + (size_t)rlo * 2048 + nx + c8);
            vr1 = *(const bf16x8*)(Vg + (size_t)(rlo + 32) * 2048 + nx + c8);
        }
        __syncthreads();  // buffer ready

        // S^T[f][r]: q = q0+l16, kv = kv0 + f*16 + quad*4 + r
        f32x4 S[4];
#pragma unroll
        for (int f = 0; f < 4; ++f) {
            bf16x8 klo = *(const bf16x8*)&sK[(f * 16 + l16) * 72 + quad * 8];
            bf16x8 khi = *(const bf16x8*)&sK[(f * 16 + l16) * 72 + 32 + quad * 8];
            S[f] = (f32x4){0.f, 0.f, 0.f, 0.f};
            S[f] = __builtin_amdgcn_mfma_f32_16x16x32_bf16(klo, qf0, S[f], 0, 0, 0);
            S[f] = __builtin_amdgcn_mfma_f32_16x16x32_bf16(khi, qf1, S[f], 0, 0, 0);
        }
        const bool diag = (it == qblk);
        const int qr16 = w * 16 + l16;  // q position within the 64-row block
#pragma unroll
        for (int f = 0; f < 4; ++f) {
            float p0, p1, p2, p3;
            {
                float sv = S[f][0] * csc;
                asm("v_exp_f32 %0, %1" : "=v"(p0) : "v"(sv));
                sv = S[f][1] * csc;
                asm("v_exp_f32 %0, %1" : "=v"(p1) : "v"(sv));
                sv = S[f][2] * csc;
                asm("v_exp_f32 %0, %1" : "=v"(p2) : "v"(sv));
                sv = S[f][3] * csc;
                asm("v_exp_f32 %0, %1" : "=v"(p3) : "v"(sv));
            }
            if (diag) {  // mask: kv_local <= q_local
                int c = f * 16 + quad * 4;
                p0 = (c + 0 <= qr16) ? p0 : 0.f;
                p1 = (c + 1 <= qr16) ? p1 : 0.f;
                p2 = (c + 2 <= qr16) ? p2 : 0.f;
                p3 = (c + 3 <= qr16) ? p3 : 0.f;
            }
            lacc += (p0 + p1) + (p2 + p3);
            unsigned int d0, d1;
            asm("v_cvt_pk_bf16_f32 %0, %1, %2" : "=v"(d0) : "v"(p0), "v"(p1));
            asm("v_cvt_pk_bf16_f32 %0, %1, %2" : "=v"(d1) : "v"(p2), "v"(p3));
            *(uint2*)&sP[w][l16 * 72 + f * 16 + quad * 4] = (uint2){d0, d1};
        }
        asm volatile("" ::: "memory");  // order P stores before reload
        bf16x8 pf0 = *(const bf16x8*)&sP[w][l16 * 72 + quad * 8];
        bf16x8 pf1 = *(const bf16x8*)&sP[w][l16 * 72 + 32 + quad * 8];
#pragma unroll
        for (int nt = 0; nt < 4; ++nt) {
            bf16x8 v0 = *(const bf16x8*)&sV[(nt * 16 + l16) * 72 + quad * 8];
            bf16x8 v1 = *(const bf16x8*)&sV[(nt * 16 + l16) * 72 + 32 + quad * 8];
            o[nt] = __builtin_amdgcn_mfma_f32_16x16x32_bf16(pf0, v0, o[nt], 0, 0, 0);
            o[nt] = __builtin_amdgcn_mfma_f32_16x16x32_bf16(pf1, v1, o[nt], 0, 0, 0);
        }
    }

    // lacc holds a partial denom for q=q0+l16 (this thread's kv subset).
    // Full denom: sum over the 4 quads (lanes sharing l16).
    lacc += __shfl_xor(lacc, 16);
    lacc += __shfl_xor(lacc, 32);
    // Output rows of this thread are q0 + quad*4 + r; their denoms live in
    // lanes (quad*4+r) (which have l16 == quad*4+r).
    float lt[4];
#pragma unroll
    for (int r = 0; r < 4; ++r) lt[r] = __shfl(lacc, quad * 4 + r);

    unsigned short* yb = y + (size_t)(b * 2048) * 1024 + h * 64;
#pragma unroll
    for (int nt = 0; nt < 4; ++nt)
#pragma unroll
        for (int r = 0; r < 4; ++r)
            yb[(size_t)(q0 + quad * 4 + r) * 1024 + nt * 16 + l16] =
                f2bf(o[nt][r] / lt[r]);
}

// -------------------------------------------------------------------------
extern "C" void kernel_launch(void* const* d_in, const int* in_sizes, int n_in,
                              void* d_out, int out_size, void* d_ws, size_t ws_size,
                              hipStream_t stream) {
    const float* x       = (const float*)d_in[0];
    const float* w_attn  = (const float*)d_in[1];
    const float* b_attn  = (const float*)d_in[2];
    const float* la_attn = (const float*)d_in[3];
    const float* lb_attn = (const float*)d_in[4];
    const float* w_proj  = (const float*)d_in[5];
    const float* b_proj  = (const float*)d_in[6];
    const float* la_proj = (const float*)d_in[7];
    const float* lb_proj = (const float*)d_in[8];
    float* out = (float*)d_out;

    char* w = (char*)d_ws;
    unsigned short* xb        = (unsigned short*)w; w += (size_t)4096 * 1024 * 2;
    unsigned short* Weff_attn = (unsigned short*)w; w += (size_t)3072 * 1024 * 2;
    unsigned short* Weff_proj = (unsigned short*)w; w += (size_t)1024 * 1024 * 2;
    unsigned short* qkv       = (unsigned short*)w; w += (size_t)4096 * 3072 * 2;
    unsigned short* Vt        = (unsigned short*)w; w += (size_t)32 * 64 * 2048 * 2;
    unsigned short* y         = (unsigned short*)w; w += (size_t)4096 * 1024 * 2;

    prep<<<20480, 256, 0, stream>>>(x, xb, w_attn, la_attn, lb_attn, Weff_attn,
                                    w_proj, la_proj, lb_proj, Weff_proj);
    gemm_bt_bias<false, true><<<dim3(24, 32), 256, 0, stream>>>(
        xb, Weff_attn, b_attn, qkv, (float*)nullptr, Vt, 4096, 3072, 1024);
    attn_kernel<<<dim3(32, 16, 2), 256, 0, stream>>>(qkv, Vt, y);
    gemm_bt_bias<true, false><<<dim3(8, 32), 256, 0, stream>>>(
        y, Weff_proj, b_proj, (unsigned short*)nullptr, out, (unsigned short*)nullptr,
        4096, 1024, 1024);
}

// Round 8
// 203.190 us; speedup vs baseline: 1.1951x; 1.0183x over previous
//
#include <hip/hip_runtime.h>

typedef __attribute__((ext_vector_type(8))) short bf16x8;
typedef __attribute__((ext_vector_type(4))) short bf16x4;
typedef __attribute__((ext_vector_type(4))) float f32x4;

__device__ __forceinline__ float bf2f(unsigned short u) {
    unsigned int x = ((unsigned int)u) << 16;
    float f;
    __builtin_memcpy(&f, &x, 4);
    return f;
}
__device__ __forceinline__ unsigned short f2bf(float f) {
    unsigned int x;
    __builtin_memcpy(&x, &f, 4);
    x += 0x7FFFu + ((x >> 16) & 1u);
    return (unsigned short)(x >> 16);
}

// Async global->LDS: HW writes lds[base + lane*16]; gptr is per-lane.
#define GLOAD_LDS16(gp, lp)                                      \
    __builtin_amdgcn_global_load_lds(                            \
        (const __attribute__((address_space(1))) void*)(gp),     \
        (__attribute__((address_space(3))) void*)(lp), 16, 0, 0)

// -------------------------------------------------------------------------
// Fused preprocessing: one launch instead of three.
// blocks [0,4096):        cast x f32 -> bf16 (4 elems/thread)
// blocks [4096,16384):    fold_lora attn  (3072x1024)
// blocks [16384,20480):   fold_lora proj  (1024x1024)
__global__ __launch_bounds__(256) void prep(
    const float* __restrict__ x, unsigned short* __restrict__ xb,
    const float* __restrict__ w_attn, const float* __restrict__ la_attn,
    const float* __restrict__ lb_attn, unsigned short* __restrict__ Weff_attn,
    const float* __restrict__ w_proj, const float* __restrict__ la_proj,
    const float* __restrict__ lb_proj, unsigned short* __restrict__ Weff_proj) {
    const int bid = blockIdx.x;
    if (bid < 4096) {
        int i = (bid * 256 + threadIdx.x) * 4;
        float4 v = *(const float4*)(x + i);
        xb[i + 0] = f2bf(v.x);
        xb[i + 1] = f2bf(v.y);
        xb[i + 2] = f2bf(v.z);
        xb[i + 3] = f2bf(v.w);
        return;
    }
    const float* W;
    const float* Ain;
    const float* Bin;
    unsigned short* Weff;
    int idx;
    if (bid < 16384) {
        idx = (bid - 4096) * 256 + threadIdx.x;
        W = w_attn; Ain = la_attn; Bin = lb_attn; Weff = Weff_attn;
    } else {
        idx = (bid - 16384) * 256 + threadIdx.x;
        W = w_proj; Ain = la_proj; Bin = lb_proj; Weff = Weff_proj;
    }
    int n = idx >> 10;
    int k = idx & 1023;
    float s = 0.f;
#pragma unroll
    for (int r = 0; r < 16; ++r)
        s += Bin[n * 16 + r] * Ain[r * 1024 + k];
    Weff[idx] = f2bf(W[idx] + 0.0625f * s);
}

// -------------------------------------------------------------------------
// C[M][N] = A[M][K] @ B[N][K]^T + bias[N].  A,B bf16; bias float; fp32 acc.
// m97 structure: global_load_lds width=16 staging, 2 barriers per K-step.
// VSPLIT (qkv GEMM): tiles with n0 >= 2048 are the V third of qkv; written
// transposed directly into Vt (replaces the transpose_v kernel).
template <bool F32OUT, bool VSPLIT>
__global__ __launch_bounds__(256) void gemm_bt_bias(
    const unsigned short* __restrict__ A, const unsigned short* __restrict__ B,
    const float* __restrict__ bias, unsigned short* __restrict__ Cb,
    float* __restrict__ Cf, unsigned short* __restrict__ Vtout,
    int M, int N, int K) {
    __shared__ unsigned short sA[128 * 32];
    __shared__ unsigned short sB[128 * 32];
    const int tid = threadIdx.x;
    const int wave = tid >> 6, lane = tid & 63;
    const int quad = lane >> 4, l16 = lane & 15;
    const int m0 = blockIdx.y * 128, n0 = blockIdx.x * 128;
    const int wm = (wave & 1) * 64, wn = (wave >> 1) * 64;

    const int srow = wave * 32 + (lane >> 2);
    const int scol = (lane & 3) * 8;
    const unsigned short* Ag = A + (size_t)(m0 + srow) * K + scol;
    const unsigned short* Bg = B + (size_t)(n0 + srow) * K + scol;
    unsigned short* sAw = sA + wave * 1024;
    unsigned short* sBw = sB + wave * 1024;
    const size_t kjump = (size_t)16 * K;

    f32x4 acc[4][4];
#pragma unroll
    for (int i = 0; i < 4; ++i)
#pragma unroll
        for (int j = 0; j < 4; ++j) acc[i][j] = (f32x4){0.f, 0.f, 0.f, 0.f};

    for (int k0 = 0; k0 < K; k0 += 32) {
        __syncthreads();  // previous tile's LDS reads done
        GLOAD_LDS16(Ag + k0, sAw);
        GLOAD_LDS16(Ag + k0 + kjump, sAw + 512);
        GLOAD_LDS16(Bg + k0, sBw);
        GLOAD_LDS16(Bg + k0 + kjump, sBw + 512);
        __syncthreads();  // drains vmcnt(0): tile resident
        bf16x8 af[4], bfr[4];
#pragma unroll
        for (int mi = 0; mi < 4; ++mi)
            af[mi] = *(const bf16x8*)&sA[(wm + mi * 16 + l16) * 32 + quad * 8];
#pragma unroll
        for (int ni = 0; ni < 4; ++ni)
            bfr[ni] = *(const bf16x8*)&sB[(wn + ni * 16 + l16) * 32 + quad * 8];
#pragma unroll
        for (int mi = 0; mi < 4; ++mi)
#pragma unroll
            for (int ni = 0; ni < 4; ++ni)
                acc[mi][ni] = __builtin_amdgcn_mfma_f32_16x16x32_bf16(
                    af[mi], bfr[ni], acc[mi][ni], 0, 0, 0);
    }
    float bv[4];
#pragma unroll
    for (int ni = 0; ni < 4; ++ni) bv[ni] = bias[n0 + wn + ni * 16 + l16];

    if (VSPLIT && n0 >= 2048) {
#pragma unroll
        for (int ni = 0; ni < 4; ++ni) {
            const int hcol = n0 + wn + ni * 16 + l16 - 2048;
#pragma unroll
            for (int mi = 0; mi < 4; ++mi) {
                const int rowtop = m0 + wm + mi * 16 + quad * 4;
                const int bb = rowtop >> 11;
                const int t = rowtop & 2047;
                bf16x4 pk;
#pragma unroll
                for (int r = 0; r < 4; ++r)
                    pk[r] = (short)f2bf(acc[mi][ni][r] + bv[ni]);
                *(bf16x4*)(Vtout +
                           ((size_t)((bb * 16 + (hcol >> 6)) * 64 + (hcol & 63))) *
                               2048 +
                           t) = pk;
            }
        }
        return;
    }

#pragma unroll
    for (int mi = 0; mi < 4; ++mi)
#pragma unroll
        for (int ni = 0; ni < 4; ++ni)
#pragma unroll
            for (int r = 0; r < 4; ++r) {
                int row = m0 + wm + mi * 16 + quad * 4 + r;
                int col = n0 + wn + ni * 16 + l16;
                float val = acc[mi][ni][r] + bv[ni];
                if (F32OUT)
                    Cf[(size_t)row * N + col] = val;
                else
                    Cb[(size_t)row * N + col] = f2bf(val);
            }
}

// -------------------------------------------------------------------------
// BM=64 variant for the proj GEMM: 64x128 tile, 4 waves of 64x32, acc 4x2.
// Grid (N/128, M/64) = (8,64) = 512 blocks = 2 blocks/CU (was 1 with 128^2),
// restoring inter-block latency hiding that proj's 256-block grid lacked.
__global__ __launch_bounds__(256) void gemm_bt_bias64(
    const unsigned short* __restrict__ A, const unsigned short* __restrict__ B,
    const float* __restrict__ bias, float* __restrict__ Cf,
    int M, int N, int K) {
    __shared__ unsigned short sA[64 * 32];
    __shared__ unsigned short sB[128 * 32];
    const int tid = threadIdx.x;
    const int wave = tid >> 6, lane = tid & 63;
    const int quad = lane >> 4, l16 = lane & 15;
    const int m0 = blockIdx.y * 64, n0 = blockIdx.x * 128;
    const int wn = wave * 32;

    // A staging: wave w stages rows w*16..w*16+15 (1 gload; 64 lanes x 16B).
    const int srowA = wave * 16 + (lane >> 2);
    // B staging: wave w stages rows w*32..w*32+31 (2 gloads).
    const int srowB = wave * 32 + (lane >> 2);
    const int scol = (lane & 3) * 8;
    const unsigned short* Ag = A + (size_t)(m0 + srowA) * K + scol;
    const unsigned short* Bg = B + (size_t)(n0 + srowB) * K + scol;
    unsigned short* sAw = sA + wave * 512;
    unsigned short* sBw = sB + wave * 1024;
    const size_t kjump = (size_t)16 * K;

    f32x4 acc[4][2];
#pragma unroll
    for (int i = 0; i < 4; ++i)
#pragma unroll
        for (int j = 0; j < 2; ++j) acc[i][j] = (f32x4){0.f, 0.f, 0.f, 0.f};

    for (int k0 = 0; k0 < K; k0 += 32) {
        __syncthreads();
        GLOAD_LDS16(Ag + k0, sAw);
        GLOAD_LDS16(Bg + k0, sBw);
        GLOAD_LDS16(Bg + k0 + kjump, sBw + 512);
        __syncthreads();
        bf16x8 af[4], bfr[2];
#pragma unroll
        for (int mi = 0; mi < 4; ++mi)
            af[mi] = *(const bf16x8*)&sA[(mi * 16 + l16) * 32 + quad * 8];
#pragma unroll
        for (int ni = 0; ni < 2; ++ni)
            bfr[ni] = *(const bf16x8*)&sB[(wn + ni * 16 + l16) * 32 + quad * 8];
#pragma unroll
        for (int mi = 0; mi < 4; ++mi)
#pragma unroll
            for (int ni = 0; ni < 2; ++ni)
                acc[mi][ni] = __builtin_amdgcn_mfma_f32_16x16x32_bf16(
                    af[mi], bfr[ni], acc[mi][ni], 0, 0, 0);
    }
    float bv[2];
#pragma unroll
    for (int ni = 0; ni < 2; ++ni) bv[ni] = bias[n0 + wn + ni * 16 + l16];
#pragma unroll
    for (int mi = 0; mi < 4; ++mi)
#pragma unroll
        for (int ni = 0; ni < 2; ++ni)
#pragma unroll
            for (int r = 0; r < 4; ++r) {
                int row = m0 + mi * 16 + quad * 4 + r;
                int col = n0 + wn + ni * 16 + l16;
                Cf[(size_t)row * N + col] = acc[mi][ni][r] + bv[ni];
            }
}

// -------------------------------------------------------------------------
// Flash attention v9: v7 + prefetch issued AFTER the second barrier.
// v7 issued next-tile K/V loads BEFORE the "buffer ready" __syncthreads,
// whose s_waitcnt vmcnt(0) drained them on the spot -- exposing full L2/HBM
// latency (~400-900 cy) on every tile of the critical 32-tile block.
// Now the loads are issued after that barrier and fly during the ~2000-cy
// compute phase; the next iteration's first barrier drains them for free.
__global__ __launch_bounds__(256) void attn_kernel(
    const unsigned short* __restrict__ qkv,  // [4096][3072] bf16
    const unsigned short* __restrict__ Vt,   // [32][64][2048] bf16
    unsigned short* __restrict__ y) {        // [4096][1024] bf16
    const int b = blockIdx.z, h = blockIdx.y;
    const int bh = b * 16 + h;
    const int qblk = (int)blockIdx.x ^ (((bh >> 3) & 1) ? 31 : 0);
    const int w = threadIdx.x >> 6, lane = threadIdx.x & 63;
    const int quad = lane >> 4, l16 = lane & 15;
    const int q0 = qblk * 64 + w * 16;
    const int ntiles = qblk + 1;

    __shared__ unsigned short sK[64 * 72];     // [kv][d]
    __shared__ unsigned short sV[64 * 72];     // [d][kv]
    __shared__ unsigned short sP[4][16 * 72];  // per-wave P [q][kv]

    const unsigned short* Qb = qkv + (size_t)(b * 2048) * 3072 + h * 64;
    const unsigned short* Kg = Qb + 1024;
    const unsigned short* Vg = Vt + (size_t)(bh * 64) * 2048;

    const int rlo = threadIdx.x >> 3;       // 0..31
    const int c8 = (threadIdx.x & 7) * 8;   // 0..56

    bf16x8 qf0 = *(const bf16x8*)(Qb + (size_t)(q0 + l16) * 3072 + quad * 8);
    bf16x8 qf1 = *(const bf16x8*)(Qb + (size_t)(q0 + l16) * 3072 + 32 + quad * 8);

    f32x4 o[4];
    float lacc = 0.f;  // scalar: all this thread's P values belong to q=q0+l16
#pragma unroll
    for (int nt = 0; nt < 4; ++nt) o[nt] = (f32x4){0.f, 0.f, 0.f, 0.f};

    const float csc = 0.125f * 1.44269504088896340736f;  // (1/sqrt 64)*log2(e)

    bf16x8 kr0 = *(const bf16x8*)(Kg + (size_t)rlo * 3072 + c8);
    bf16x8 kr1 = *(const bf16x8*)(Kg + (size_t)(rlo + 32) * 3072 + c8);
    bf16x8 vr0 = *(const bf16x8*)(Vg + (size_t)rlo * 2048 + c8);
    bf16x8 vr1 = *(const bf16x8*)(Vg + (size_t)(rlo + 32) * 2048 + c8);

    for (int it = 0; it < ntiles; ++it) {
        const int kv0 = it * 64;
        __syncthreads();  // buffer free; drains last iter's prefetch (cheap)
        *(bf16x8*)&sK[rlo * 72 + c8] = kr0;
        *(bf16x8*)&sK[(rlo + 32) * 72 + c8] = kr1;
        *(bf16x8*)&sV[rlo * 72 + c8] = vr0;
        *(bf16x8*)&sV[(rlo + 32) * 72 + c8] = vr1;
        __syncthreads();  // buffer ready (no vmem outstanding here)
        if (it + 1 < ntiles) {  // prefetch next tile: in flight during compute
            const int nx = kv0 + 64;
            kr0 = *(const bf16x8*)(Kg + (size_t)(nx + rlo) * 3072 + c8);
            kr1 = *(const bf16x8*)(Kg + (size_t)(nx + rlo + 32) * 3072 + c8);
            vr0 = *(const bf16x8*)(Vg + (size_t)rlo * 2048 + nx + c8);
            vr1 = *(const bf16x8*)(Vg + (size_t)(rlo + 32) * 2048 + nx + c8);
        }

        // S^T[f][r]: q = q0+l16, kv = kv0 + f*16 + quad*4 + r
        f32x4 S[4];
#pragma unroll
        for (int f = 0; f < 4; ++f) {
            bf16x8 klo = *(const bf16x8*)&sK[(f * 16 + l16) * 72 + quad * 8];
            bf16x8 khi = *(const bf16x8*)&sK[(f * 16 + l16) * 72 + 32 + quad * 8];
            S[f] = (f32x4){0.f, 0.f, 0.f, 0.f};
            S[f] = __builtin_amdgcn_mfma_f32_16x16x32_bf16(klo, qf0, S[f], 0, 0, 0);
            S[f] = __builtin_amdgcn_mfma_f32_16x16x32_bf16(khi, qf1, S[f], 0, 0, 0);
        }
        const bool diag = (it == qblk);
        const int qr16 = w * 16 + l16;  // q position within the 64-row block
#pragma unroll
        for (int f = 0; f < 4; ++f) {
            float p0, p1, p2, p3;
            {
                float sv = S[f][0] * csc;
                asm("v_exp_f32 %0, %1" : "=v"(p0) : "v"(sv));
                sv = S[f][1] * csc;
                asm("v_exp_f32 %0, %1" : "=v"(p1) : "v"(sv));
                sv = S[f][2] * csc;
                asm("v_exp_f32 %0, %1" : "=v"(p2) : "v"(sv));
                sv = S[f][3] * csc;
                asm("v_exp_f32 %0, %1" : "=v"(p3) : "v"(sv));
            }
            if (diag) {  // mask: kv_local <= q_local
                int c = f * 16 + quad * 4;
                p0 = (c + 0 <= qr16) ? p0 : 0.f;
                p1 = (c + 1 <= qr16) ? p1 : 0.f;
                p2 = (c + 2 <= qr16) ? p2 : 0.f;
                p3 = (c + 3 <= qr16) ? p3 : 0.f;
            }
            lacc += (p0 + p1) + (p2 + p3);
            unsigned int d0, d1;
            asm("v_cvt_pk_bf16_f32 %0, %1, %2" : "=v"(d0) : "v"(p0), "v"(p1));
            asm("v_cvt_pk_bf16_f32 %0, %1, %2" : "=v"(d1) : "v"(p2), "v"(p3));
            *(uint2*)&sP[w][l16 * 72 + f * 16 + quad * 4] = (uint2){d0, d1};
        }
        asm volatile("" ::: "memory");  // order P stores before reload
        bf16x8 pf0 = *(const bf16x8*)&sP[w][l16 * 72 + quad * 8];
        bf16x8 pf1 = *(const bf16x8*)&sP[w][l16 * 72 + 32 + quad * 8];
#pragma unroll
        for (int nt = 0; nt < 4; ++nt) {
            bf16x8 v0 = *(const bf16x8*)&sV[(nt * 16 + l16) * 72 + quad * 8];
            bf16x8 v1 = *(const bf16x8*)&sV[(nt * 16 + l16) * 72 + 32 + quad * 8];
            o[nt] = __builtin_amdgcn_mfma_f32_16x16x32_bf16(pf0, v0, o[nt], 0, 0, 0);
            o[nt] = __builtin_amdgcn_mfma_f32_16x16x32_bf16(pf1, v1, o[nt], 0, 0, 0);
        }
    }

    // lacc holds a partial denom for q=q0+l16 (this thread's kv subset).
    // Full denom: sum over the 4 quads (lanes sharing l16).
    lacc += __shfl_xor(lacc, 16);
    lacc += __shfl_xor(lacc, 32);
    // Output rows of this thread are q0 + quad*4 + r; their denoms live in
    // lanes (quad*4+r) (which have l16 == quad*4+r).
    float lt[4];
#pragma unroll
    for (int r = 0; r < 4; ++r) lt[r] = __shfl(lacc, quad * 4 + r);

    unsigned short* yb = y + (size_t)(b * 2048) * 1024 + h * 64;
#pragma unroll
    for (int nt = 0; nt < 4; ++nt)
#pragma unroll
        for (int r = 0; r < 4; ++r)
            yb[(size_t)(q0 + quad * 4 + r) * 1024 + nt * 16 + l16] =
                f2bf(o[nt][r] / lt[r]);
}

// -------------------------------------------------------------------------
extern "C" void kernel_launch(void* const* d_in, const int* in_sizes, int n_in,
                              void* d_out, int out_size, void* d_ws, size_t ws_size,
                              hipStream_t stream) {
    const float* x       = (const float*)d_in[0];
    const float* w_attn  = (const float*)d_in[1];
    const float* b_attn  = (const float*)d_in[2];
    const float* la_attn = (const float*)d_in[3];
    const float* lb_attn = (const float*)d_in[4];
    const float* w_proj  = (const float*)d_in[5];
    const float* b_proj  = (const float*)d_in[6];
    const float* la_proj = (const float*)d_in[7];
    const float* lb_proj = (const float*)d_in[8];
    float* out = (float*)d_out;

    char* w = (char*)d_ws;
    unsigned short* xb        = (unsigned short*)w; w += (size_t)4096 * 1024 * 2;
    unsigned short* Weff_attn = (unsigned short*)w; w += (size_t)3072 * 1024 * 2;
    unsigned short* Weff_proj = (unsigned short*)w; w += (size_t)1024 * 1024 * 2;
    unsigned short* qkv       = (unsigned short*)w; w += (size_t)4096 * 3072 * 2;
    unsigned short* Vt        = (unsigned short*)w; w += (size_t)32 * 64 * 2048 * 2;
    unsigned short* y         = (unsigned short*)w; w += (size_t)4096 * 1024 * 2;

    prep<<<20480, 256, 0, stream>>>(x, xb, w_attn, la_attn, lb_attn, Weff_attn,
                                    w_proj, la_proj, lb_proj, Weff_proj);
    gemm_bt_bias<false, true><<<dim3(24, 32), 256, 0, stream>>>(
        xb, Weff_attn, b_attn, qkv, (float*)nullptr, Vt, 4096, 3072, 1024);
    attn_kernel<<<dim3(32, 16, 2), 256, 0, stream>>>(qkv, Vt, y);
    gemm_bt_bias64<<<dim3(8, 64), 256, 0, stream>>>(
        y, Weff_proj, b_proj, out, 4096, 1024, 1024);
}